// Round 12
// baseline (842.819 us; speedup 1.0000x reference)
//
#include <hip/hip_runtime.h>
#include <hip/hip_bf16.h>

#define NN 20000
#define NP 20080            // padded to 80*251 (GEMM row tiles)
#define NE 320000
#define RR 8
#define DD 256
#define LL 6
#define EED 32
#define BB 64
#define KK 32
#define MM (NN * RR)        // 160000 segments, key = dst*8 + rel
#define NSB 79              // scan blocks: ceil(160000 / 2048)
#define BMR 80              // GEMM row-tile
#define NGB 251             // GEMM grid = NP / BMR (<= 256 CUs -> single round)
#define YROW 2304           // Y row: 9 tiles of 256 (r=0..7 relations, 8=self)
#define YROWB 4608          // Y row bytes
#define HSTR 260            // eterm6 Hs row stride (floats)
#define HSTRB 264           // ymm bf16 Hs row stride (ushorts): quad spread 2x2-way

typedef __bf16 bf8 __attribute__((ext_vector_type(8)));
typedef float f4 __attribute__((ext_vector_type(4)));

__device__ inline float lo2f(unsigned v) { return __uint_as_float(v << 16); }
__device__ inline float hi2f(unsigned v) { return __uint_as_float(v & 0xffff0000u); }
__device__ inline unsigned short f2bf(float f) {
    unsigned u = __float_as_uint(f);
    return (unsigned short)((u + 0x7fff + ((u >> 16) & 1)) >> 16);
}
__device__ inline unsigned pack2(float lo, float hi) {
    return (unsigned)f2bf(lo) | ((unsigned)f2bf(hi) << 16);
}

// global->LDS direct copy, 16B per lane. LDS dest linear (wave base + lane*16);
// swizzle lives in the per-lane GLOBAL source address (m173 pattern).
#define GLOAD_LDS16(src, dst)                                                  \
    __builtin_amdgcn_global_load_lds(                                          \
        (const __attribute__((address_space(1))) unsigned int*)(src),          \
        (__attribute__((address_space(3))) unsigned int*)(dst), 16, 0, 0)

// Raw phase barrier: order LDS ops only; global stores / loads stay in flight.
// NO memory clobber (round-2 lesson: clobber -> vmcnt(0) drain); sched_barrier
// fences compiler motion (rule #18).
#define LGKM_BARRIER()                                                         \
    do {                                                                       \
        __builtin_amdgcn_sched_barrier(0);                                     \
        asm volatile("s_waitcnt lgkmcnt(0)");                                  \
        __builtin_amdgcn_s_barrier();                                          \
        __builtin_amdgcn_sched_barrier(0);                                     \
    } while (0)

// ---------------- CSR build (once per call) ----------------

__global__ __launch_bounds__(256) void hist_kernel(const int* __restrict__ dstv,
                                                   const int* __restrict__ typev,
                                                   int* __restrict__ hist) {
    int e = blockIdx.x * 256 + threadIdx.x;
    if (e < NE) atomicAdd(&hist[dstv[e] * 8 + typev[e]], 1);
}

__global__ __launch_bounds__(256) void scan1_kernel(const int* __restrict__ hist,
                                                    int* __restrict__ excl,
                                                    int* __restrict__ bsums) {
    __shared__ int tmp[256];
    int tid = threadIdx.x;
    int base = blockIdx.x * 2048 + tid * 8;
    int v[8]; int s = 0;
#pragma unroll
    for (int i = 0; i < 8; ++i) {
        v[i] = (base + i < MM) ? hist[base + i] : 0;
        s += v[i];
    }
    tmp[tid] = s;
    __syncthreads();
    for (int off = 1; off < 256; off <<= 1) {
        int t = (tid >= off) ? tmp[tid - off] : 0;
        __syncthreads();
        tmp[tid] += t;
        __syncthreads();
    }
    int run = tmp[tid] - s;
#pragma unroll
    for (int i = 0; i < 8; ++i) {
        if (base + i < MM) excl[base + i] = run;
        run += v[i];
    }
    if (tid == 255) bsums[blockIdx.x] = tmp[255];
}

__global__ __launch_bounds__(128) void scan2_kernel(int* __restrict__ bsums) {
    __shared__ int tmp[128];
    int tid = threadIdx.x;
    int orig = (tid < NSB) ? bsums[tid] : 0;
    tmp[tid] = orig;
    __syncthreads();
    for (int off = 1; off < 128; off <<= 1) {
        int t = (tid >= off) ? tmp[tid - off] : 0;
        __syncthreads();
        tmp[tid] += t;
        __syncthreads();
    }
    if (tid < NSB) bsums[tid] = tmp[tid] - orig;
}

__global__ __launch_bounds__(256) void add_off_kernel(const int* __restrict__ excl,
                                                      const int* __restrict__ bsums,
                                                      int* __restrict__ seg_start,
                                                      int* __restrict__ cursor) {
    int i = blockIdx.x * 256 + threadIdx.x;
    if (i < MM) {
        int v = excl[i] + bsums[i >> 11];
        seg_start[i] = v;
        cursor[i] = v;
    }
    if (i == 0) seg_start[MM] = NE;
}

// scatter: pre-bake the Y gather byte-offset (src row + relation block) so the
// per-layer gather needs ZERO relation logic.
__global__ __launch_bounds__(256) void sort_scatter_kernel(
    const int* __restrict__ srcv, const int* __restrict__ dstv,
    const int* __restrict__ typev, int* __restrict__ cursor,
    int* __restrict__ esrcY, int* __restrict__ eid) {
    int e = blockIdx.x * 256 + threadIdx.x;
    if (e < NE) {
        int key = dstv[e] * 8 + typev[e];
        int pos = atomicAdd(&cursor[key], 1);
        esrcY[pos] = srcv[e] * YROWB + typev[e] * 512;
        eid[pos]   = e;
    }
}

__global__ __launch_bounds__(256) void invdeg_kernel(const int* __restrict__ seg_start,
                                                     float* __restrict__ invdeg) {
    int i = blockIdx.x * 256 + threadIdx.x;
    if (i < NN) {
        int d = seg_start[i * 8 + 8] - seg_start[i * 8];
        invdeg[i] = 1.0f / (float)max(d, 1);
    }
}

// ---------------- once-per-call precomputes ----------------

// Batched-gather eagg (round-5 lesson: serial dependent eid->ee chains left the
// wave with ~2 loads in flight -> 52us latency-bound. Issue 4 eid + 4 row loads
// per batch before accumulating, clamped indices; avg segment = 2 edges.)
__global__ __launch_bounds__(256) void eagg_kernel(
    const int* __restrict__ seg_start, const int* __restrict__ eid,
    const float* __restrict__ ee, const float* __restrict__ invdeg,
    unsigned short* __restrict__ eaggbf) {
    int tid = threadIdx.x;
    int s = blockIdx.x * 8 + (tid >> 5);
    int j = tid & 31;
    int n = s >> 3, r = s & 7;
    int j0 = seg_start[s], j1 = seg_start[s + 1];
    float sum = 0.0f;
#pragma unroll 1
    for (int p = j0; p < j1; p += 4) {
        int rem = j1 - p;
        int e4[4];
        float fv[4];
#pragma unroll
        for (int t = 0; t < 4; ++t)
            e4[t] = eid[(t < rem) ? p + t : p];        // always-valid index
#pragma unroll
        for (int t = 0; t < 4; ++t)
            fv[t] = ee[(size_t)e4[t] * EED + j];
#pragma unroll
        for (int t = 0; t < 4; ++t)
            sum += (t < rem) ? fv[t] : 0.0f;
    }
    eaggbf[(size_t)n * DD + r * EED + j] = f2bf(sum * invdeg[n]);
}

// Whe split-K over 8 d-chunks of 32, fp32 atomics (Whe pre-zeroed)
__global__ __launch_bounds__(256) void whe_kernel(const float* __restrict__ We,
                                                  const float* __restrict__ W,
                                                  float* __restrict__ Whe) {
    __shared__ float WeS[EED * 32];
    int b = blockIdx.x;
    int l = b >> 6;
    int r = (b >> 3) & 7;
    int dc = b & 7;
    int tid = threadIdx.x;
    {
        int j = tid >> 3, dl = (tid & 7) * 4;
        *(float4*)&WeS[j * 32 + dl] =
            *(const float4*)&We[(size_t)l * EED * DD + (size_t)j * DD + dc * 32 + dl];
    }
    __syncthreads();
    const float* Wr = W + ((size_t)l * 8 + r) * DD * DD + (size_t)dc * 32 * DD;
    float acc[EED];
#pragma unroll
    for (int j = 0; j < EED; ++j) acc[j] = 0.0f;
    for (int dl = 0; dl < 32; ++dl) {
        float w = Wr[(size_t)dl * DD + tid];
#pragma unroll
        for (int j = 0; j < EED; ++j) acc[j] += WeS[j * 32 + dl] * w;
    }
    float* outp = Whe + (size_t)l * DD * DD + r * EED * DD + tid;
#pragma unroll
    for (int j = 0; j < EED; ++j) unsafeAtomicAdd(&outp[j * DD], acc[j]);
}

// B pre-swizzle into MFMA fragment order (bf16).
// Tile order rt: 0..7 -> W[r=rt], 8 -> Wself, 9 -> Whe.
// Bsw[l][(((rt*8+kb)*4+quad)*256+f)*8+j] = B_l[rt][kb*32+quad*8+j][f]
__global__ __launch_bounds__(256) void bswz_kernel(const float* __restrict__ W,
                                                   const float* __restrict__ Wself,
                                                   const float* __restrict__ Whe,
                                                   unsigned short* __restrict__ Bsw) {
    int gid = blockIdx.x * 256 + threadIdx.x;
    int f = gid & 255;
    int t = gid >> 8;
    int quad = t & 3; t >>= 2;
    int kb = t & 7; t >>= 3;
    int p = t % 10, l = t / 10;
    const float* base = (p <= 7) ? W + ((size_t)l * 8 + p) * DD * DD
                      : (p == 8) ? Wself + (size_t)l * DD * DD
                                 : Whe + (size_t)l * DD * DD;
    int k0 = kb * 32 + quad * 8;
    unsigned pk[4];
#pragma unroll
    for (int jj = 0; jj < 4; ++jj)
        pk[jj] = pack2(base[(size_t)(k0 + 2 * jj) * DD + f],
                       base[(size_t)(k0 + 2 * jj + 1) * DD + f]);
    uint4 v = make_uint4(pk[0], pk[1], pk[2], pk[3]);
    *(uint4*)&Bsw[(size_t)gid * 8] = v;
}

__global__ __launch_bounds__(256) void init_x_kernel(float* __restrict__ xA,
                                                     float* __restrict__ xB,
                                                     unsigned short* __restrict__ xbfA,
                                                     unsigned short* __restrict__ xbfB) {
    int i = blockIdx.x * 256 + threadIdx.x;
    ((float4*)xA)[i] = make_float4(1.f, 1.f, 1.f, 1.f);
    ((float4*)xB)[i] = make_float4(1.f, 1.f, 1.f, 1.f);   // pad rows stay valid all layers
    ((uint2*)xbfA)[i] = make_uint2(0x3f803f80u, 0x3f803f80u);
    ((uint2*)xbfB)[i] = make_uint2(0x3f803f80u, 0x3f803f80u);
}

// ---------------- eterm precompute for ALL layers (x-independent) ----------------
// eterm_l = eaggbf @ Whe_l does not depend on x: all 6 layers computed once.
// Plain stores (NT poisoned the L3 in round 9). Runs once -> keeps the simple
// f32-Hs epilogue.
__global__ __launch_bounds__(512) void eterm6_kernel(
    const unsigned short* __restrict__ eaggbf, const unsigned short* __restrict__ Bsw,
    unsigned short* __restrict__ etermb6) {
    __shared__ __align__(16) unsigned char smem[40960 + BMR * HSTR * 4];
    unsigned char* As = smem;
    float* Hs = (float*)(smem + 40960);
    int tid = threadIdx.x;
    int wv = tid >> 6, lane = tid & 63;
    int row0 = blockIdx.x * BMR;
    int m = lane & 15, quad = lane >> 4;
    int col = wv * 32 + m;

#pragma unroll
    for (int i = 0; i < 5; ++i) {
        int bc = i * 512 + wv * 64;
        int c = bc + lane;
        int row = c >> 5, sc = c & 31, scs = sc ^ (row & 31);
        GLOAD_LDS16(eaggbf + (size_t)(row0 + row) * DD + scs * 8, As + (size_t)c * 16);
    }
    __syncthreads();                                 // A tile ready

#pragma unroll 1
    for (int l = 0; l < LL; ++l) {
        const unsigned short* Bswl = Bsw + (size_t)l * 2560 * DD;
        bf8 breg[2][2];
#pragma unroll
        for (int nt = 0; nt < 2; ++nt) {
            breg[0][nt] = *(const bf8*)&Bswl[(((size_t)72 * 4 + quad) * 256 + col + nt * 16) * 8];
            breg[1][nt] = *(const bf8*)&Bswl[(((size_t)73 * 4 + quad) * 256 + col + nt * 16) * 8];
        }
        f4 acc[5][2] = {};
#pragma unroll
        for (int kb = 0; kb < 8; ++kb) {
            bf8 afr[5];
#pragma unroll
            for (int mt = 0; mt < 5; ++mt) {
                int rowl = mt * 16 + m;
                afr[mt] = *(bf8*)&As[rowl * 512 + (((kb * 4 + quad) ^ (rowl & 31)) * 16)];
            }
#pragma unroll
            for (int mt = 0; mt < 5; ++mt)
#pragma unroll
                for (int nt = 0; nt < 2; ++nt)
                    acc[mt][nt] = __builtin_amdgcn_mfma_f32_16x16x32_bf16(
                        afr[mt], breg[kb & 1][nt], acc[mt][nt], 0, 0, 0);
            int gn = 72 + kb + 2;
            if (gn < 80) {
#pragma unroll
                for (int nt = 0; nt < 2; ++nt)
                    breg[kb & 1][nt] = *(const bf8*)&Bswl[((size_t)gn * 4 + quad) * 2048
                                                          + ((size_t)(col + nt * 16)) * 8];
            }
        }
        if (l > 0) LGKM_BARRIER();
#pragma unroll
        for (int mt = 0; mt < 5; ++mt)
#pragma unroll
            for (int nt = 0; nt < 2; ++nt)
#pragma unroll
                for (int rg = 0; rg < 4; ++rg)
                    Hs[(mt * 16 + quad * 4 + rg) * HSTR + wv * 32 + nt * 16 + m] = acc[mt][nt][rg];
        LGKM_BARRIER();
        unsigned short* outl = etermb6 + (size_t)l * NP * DD;
#pragma unroll
        for (int c2 = 0; c2 < 10; ++c2) {
            int li = c2 * 512 + tid;
            int row = li >> 6, u4 = li & 63;
            float4 v = *(float4*)&Hs[row * HSTR + u4 * 4];
            *(uint2*)&outl[(size_t)(row0 + row) * DD + u4 * 4] =
                make_uint2(pack2(v.x, v.y), pack2(v.z, v.w));
        }
    }
}

// ---------------- k1: dense GEMM  Y = x @ [W0..W7|Wself] ----------------
// transform-then-aggregate: Y[n][rt*256+f] = sum_k x[n][k] * Wcat[rt][k][f],
// rt 0..8. A (80 x 256) staged once; B streams L2-resident with distance-2
// register prefetch. Plain stores (keep Y in L3 for aggln's gather).
// Round-12: OCCUPANCY lever. r7-r10 showed ymm pinned at ~2.2 TB/s effective
// write with LDS 124KB -> 1 block/CU (8 waves). Epilogue now stages through a
// bf16 HALF-tile Hsb (40 rows x HSTRB, 2 passes/tile): LDS = 40960 + 21120 =
// 62080 -> 2 blocks/CU (16 waves) to double posted-store parallelism. f2bf
// moves to the LDS-write side; global stores are straight uint2 copies.
__global__ __launch_bounds__(512) void ymm_kernel(
    const unsigned short* __restrict__ xbfin, const unsigned short* __restrict__ Bswl,
    unsigned short* __restrict__ Y) {
    __shared__ __align__(16) unsigned char smem[40960 + 40 * HSTRB * 2];
    unsigned char* As = smem;
    unsigned short* Hsb = (unsigned short*)(smem + 40960);
    int tid = threadIdx.x;
    int wv = tid >> 6, lane = tid & 63;
    int row0 = blockIdx.x * BMR;
    int m = lane & 15, quad = lane >> 4;

#pragma unroll
    for (int i = 0; i < 5; ++i) {
        int bc = i * 512 + wv * 64;
        int c = bc + lane;
        int row = c >> 5, sc = c & 31, scs = sc ^ (row & 31);
        GLOAD_LDS16(xbfin + (size_t)(row0 + row) * DD + scs * 8, As + (size_t)c * 16);
    }
    bf8 breg[2][2];
#pragma unroll
    for (int nt = 0; nt < 2; ++nt) {
        breg[0][nt] = *(const bf8*)&Bswl[((size_t)quad * 256 + wv * 32 + nt * 16 + m) * 8];
        breg[1][nt] = *(const bf8*)&Bswl[(((size_t)4 + quad) * 256 + wv * 32 + nt * 16 + m) * 8];
    }
    __syncthreads();                                 // A tile ready (vmcnt drain)

#pragma unroll 1
    for (int rt = 0; rt < 9; ++rt) {
        f4 acc[5][2] = {};
#pragma unroll
        for (int kb = 0; kb < 8; ++kb) {
            bf8 afr[5];
#pragma unroll
            for (int mt = 0; mt < 5; ++mt) {
                int rowl = mt * 16 + m;
                afr[mt] = *(bf8*)&As[rowl * 512 + (((kb * 4 + quad) ^ (rowl & 31)) * 16)];
            }
#pragma unroll
            for (int mt = 0; mt < 5; ++mt)
#pragma unroll
                for (int nt = 0; nt < 2; ++nt)
                    acc[mt][nt] = __builtin_amdgcn_mfma_f32_16x16x32_bf16(
                        afr[mt], breg[kb & 1][nt], acc[mt][nt], 0, 0, 0);
            int gn = rt * 8 + kb + 2;
            if (gn < 72) {                           // 9 tiles -> fragments 0..71
#pragma unroll
                for (int nt = 0; nt < 2; ++nt)
                    breg[kb & 1][nt] = *(const bf8*)&Bswl[((size_t)gn * 4 + quad) * 2048
                                                          + ((size_t)(wv * 32 + nt * 16 + m)) * 8];
            }
        }
        // ---- per-tile epilogue: 2 passes of 40 rows through bf16 Hsb ----
#pragma unroll
        for (int p = 0; p < 2; ++p) {
            if (rt > 0 || p > 0) LGKM_BARRIER();     // prior pass's Hsb reads done
#pragma unroll
            for (int mt = 0; mt < 5; ++mt)
#pragma unroll
                for (int nt = 0; nt < 2; ++nt)
#pragma unroll
                    for (int rg = 0; rg < 4; ++rg) {
                        int r = mt * 16 + quad * 4 + rg;
                        if (r >= p * 40 && r < p * 40 + 40)
                            Hsb[(r - p * 40) * HSTRB + wv * 32 + nt * 16 + m] =
                                f2bf(acc[mt][nt][rg]);
                    }
            LGKM_BARRIER();                          // Hsb writes visible
#pragma unroll
            for (int it = 0; it < 5; ++it) {
                int li = it * 512 + tid;
                int row = li >> 6, u4 = li & 63;
                uint2 v = *(uint2*)&Hsb[row * HSTRB + u4 * 4];
                *(uint2*)&Y[(size_t)(row0 + p * 40 + row) * YROW + rt * 256 + u4 * 4] = v;
            }
        }
    }
}

// ---------------- k2: fused gather + LN + residual (latency regime) ----------------
// TWO nodes per wave, software-pipelined: each wave owns nodes 2w,2w+1 with
// independent 16-deep batches (gvA,gvB), doubling in-flight loads and
// overlapping B-issue with A-accumulate. Wave-uniform branches only; relation
// pre-baked into esrcY byte offsets.
__global__ __launch_bounds__(512) void aggln_kernel(
    const int* __restrict__ seg_start, const int* __restrict__ esrcY,
    const unsigned short* __restrict__ Y, const unsigned short* __restrict__ eterml,
    const float* __restrict__ xin, const float* __restrict__ gl,
    const float* __restrict__ bl, float* __restrict__ xout,
    unsigned short* __restrict__ xbfout) {
    int tid = threadIdx.x;
    int wv = tid >> 6, lane = tid & 63;
    int nA = (blockIdx.x * 8 + wv) * 2;             // grid 1250 -> nA,nB < 20000 exact
    int nB = nA + 1;
    const char* Yb = (const char*)Y;
    size_t lo8 = (size_t)(lane * 8);
    int jA = seg_start[nA * 8], jA1 = seg_start[nA * 8 + 8];
    int jB = seg_start[nB * 8], jB1 = seg_start[nB * 8 + 8];
    float idgA = 1.0f / (float)max(jA1 - jA, 1);
    float idgB = 1.0f / (float)max(jB1 - jB, 1);

    // issue both nodes' first gather batches (32 loads in flight / lane group)
    uint2 gvA[16], gvB[16];
#pragma unroll
    for (int t = 0; t < 16; ++t) {
        int ja = (jA + t < jA1) ? jA + t : jA;      // clamp: always-valid addr
        int jb = (jB + t < jB1) ? jB + t : jB;
        gvA[t] = *(const uint2*)(Yb + (size_t)(unsigned)esrcY[ja] + lo8);
        gvB[t] = *(const uint2*)(Yb + (size_t)(unsigned)esrcY[jb] + lo8);
    }
    // hoisted independent per-node loads (overlap the gathers)
    size_t xiA = (size_t)nA * DD + lane * 4;
    size_t xiB = (size_t)nB * DD + lane * 4;
    uint2 svA = *(const uint2*)(Yb + (size_t)nA * YROWB + 4096 + lo8);
    uint2 svB = *(const uint2*)(Yb + (size_t)nB * YROWB + 4096 + lo8);
    uint2 evA = *(const uint2*)&eterml[(size_t)nA * DD + lane * 4];
    uint2 evB = *(const uint2*)&eterml[(size_t)nB * DD + lane * 4];
    float4 xvA = *(const float4*)&xin[xiA];
    float4 xvB = *(const float4*)&xin[xiB];
    float4 g  = *(const float4*)&gl[lane * 4];
    float4 bb = *(const float4*)&bl[lane * 4];

    float aA0 = 0.f, aA1 = 0.f, aA2 = 0.f, aA3 = 0.f;
    float aB0 = 0.f, aB1 = 0.f, aB2 = 0.f, aB3 = 0.f;
#pragma unroll 1
    while (jA < jA1 || jB < jB1) {                  // wave-uniform condition
        if (jA < jA1) {
            int rem = jA1 - jA;
#pragma unroll
            for (int t = 0; t < 16; ++t) {
                unsigned vx = (t < rem) ? gvA[t].x : 0u;
                unsigned vy = (t < rem) ? gvA[t].y : 0u;
                aA0 += lo2f(vx); aA1 += hi2f(vx);
                aA2 += lo2f(vy); aA3 += hi2f(vy);
            }
            jA += 16;
            if (jA < jA1) {                          // re-issue next A batch
#pragma unroll
                for (int t = 0; t < 16; ++t) {
                    int ja = (jA + t < jA1) ? jA + t : jA;
                    gvA[t] = *(const uint2*)(Yb + (size_t)(unsigned)esrcY[ja] + lo8);
                }
            }
        }
        if (jB < jB1) {
            int rem = jB1 - jB;
#pragma unroll
            for (int t = 0; t < 16; ++t) {
                unsigned vx = (t < rem) ? gvB[t].x : 0u;
                unsigned vy = (t < rem) ? gvB[t].y : 0u;
                aB0 += lo2f(vx); aB1 += hi2f(vx);
                aB2 += lo2f(vy); aB3 += hi2f(vy);
            }
            jB += 16;
            if (jB < jB1) {                          // re-issue next B batch
#pragma unroll
                for (int t = 0; t < 16; ++t) {
                    int jb = (jB + t < jB1) ? jB + t : jB;
                    gvB[t] = *(const uint2*)(Yb + (size_t)(unsigned)esrcY[jb] + lo8);
                }
            }
        }
    }

    // ---- finalize node A ----
    {
        float h0 = aA0 * idgA + lo2f(svA.x) + lo2f(evA.x);
        float h1 = aA1 * idgA + hi2f(svA.x) + hi2f(evA.x);
        float h2 = aA2 * idgA + lo2f(svA.y) + lo2f(evA.y);
        float h3 = aA3 * idgA + hi2f(svA.y) + hi2f(evA.y);
        float s = h0 + h1 + h2 + h3;
        float q = h0 * h0 + h1 * h1 + h2 * h2 + h3 * h3;
#pragma unroll
        for (int off = 32; off; off >>= 1) {
            s += __shfl_xor(s, off);
            q += __shfl_xor(q, off);
        }
        float mu  = s * (1.0f / DD);
        float var = q * (1.0f / DD) - mu * mu;
        float rs  = rsqrtf(var + 1e-5f);
        float4 o;
        o.x = fmaxf((h0 - mu) * rs * g.x + bb.x, 0.0f) + xvA.x;
        o.y = fmaxf((h1 - mu) * rs * g.y + bb.y, 0.0f) + xvA.y;
        o.z = fmaxf((h2 - mu) * rs * g.z + bb.z, 0.0f) + xvA.z;
        o.w = fmaxf((h3 - mu) * rs * g.w + bb.w, 0.0f) + xvA.w;
        *(float4*)&xout[xiA] = o;
        *(uint2*)&xbfout[xiA] = make_uint2(pack2(o.x, o.y), pack2(o.z, o.w));
    }
    // ---- finalize node B ----
    {
        float h0 = aB0 * idgB + lo2f(svB.x) + lo2f(evB.x);
        float h1 = aB1 * idgB + hi2f(svB.x) + hi2f(evB.x);
        float h2 = aB2 * idgB + lo2f(svB.y) + lo2f(evB.y);
        float h3 = aB3 * idgB + hi2f(svB.y) + hi2f(evB.y);
        float s = h0 + h1 + h2 + h3;
        float q = h0 * h0 + h1 * h1 + h2 * h2 + h3 * h3;
#pragma unroll
        for (int off = 32; off; off >>= 1) {
            s += __shfl_xor(s, off);
            q += __shfl_xor(q, off);
        }
        float mu  = s * (1.0f / DD);
        float var = q * (1.0f / DD) - mu * mu;
        float rs  = rsqrtf(var + 1e-5f);
        float4 o;
        o.x = fmaxf((h0 - mu) * rs * g.x + bb.x, 0.0f) + xvB.x;
        o.y = fmaxf((h1 - mu) * rs * g.y + bb.y, 0.0f) + xvB.y;
        o.z = fmaxf((h2 - mu) * rs * g.z + bb.z, 0.0f) + xvB.z;
        o.w = fmaxf((h3 - mu) * rs * g.w + bb.w, 0.0f) + xvB.w;
        *(float4*)&xout[xiB] = o;
        *(uint2*)&xbfout[xiB] = make_uint2(pack2(o.x, o.y), pack2(o.z, o.w));
    }
}

__global__ __launch_bounds__(256) void score_kernel(
    const int* __restrict__ batch, const float* __restrict__ x,
    const float* __restrict__ rel_emb, float* __restrict__ out) {
    int tid = threadIdx.x;
    int wave = tid >> 6, lane = tid & 63;
    int idx = blockIdx.x * 4 + wave;
    int s = batch[idx * 3 + 0], t = batch[idx * 3 + 1], r = batch[idx * 3 + 2];
    float4 sv = *(const float4*)&x[(size_t)s * DD + lane * 4];
    float4 tv = *(const float4*)&x[(size_t)t * DD + lane * 4];
    float4 rv = *(const float4*)&rel_emb[(size_t)r * DD + lane * 4];
    float sum = sv.x * rv.x * tv.x + sv.y * rv.y * tv.y +
                sv.z * rv.z * tv.z + sv.w * rv.w * tv.w;
#pragma unroll
    for (int off = 32; off; off >>= 1) sum += __shfl_xor(sum, off);
    if (lane == 0) out[idx] = sum;
}

extern "C" void kernel_launch(void* const* d_in, const int* in_sizes, int n_in,
                              void* d_out, int out_size, void* d_ws, size_t ws_size,
                              hipStream_t stream) {
    const int*   edge_index = (const int*)d_in[0];
    const int*   srcv   = edge_index;
    const int*   dstv   = edge_index + NE;
    const int*   typev  = (const int*)d_in[1];
    const float* ee     = (const float*)d_in[2];
    const int*   batch  = (const int*)d_in[3];
    const float* W      = (const float*)d_in[4];
    const float* Wself  = (const float*)d_in[5];
    const float* We     = (const float*)d_in[6];
    const float* gamma  = (const float*)d_in[7];
    const float* beta   = (const float*)d_in[8];
    const float* rel_emb= (const float*)d_in[9];
    float* out = (float*)d_out;

    // workspace layout (~245 MB)
    float* xA     = (float*)d_ws;                          // NP*256 f32
    float* xB     = xA + (size_t)NP * DD;                  // NP*256 f32
    float* Whe    = xB + (size_t)NP * DD;                  // L*256*256 f32
    float* invdeg = Whe + (size_t)LL * DD * DD;            // NN f32
    unsigned short* xbfA   = (unsigned short*)(invdeg + NN);          // NP*256
    unsigned short* xbfB   = xbfA + (size_t)NP * DD;                  // NP*256
    unsigned short* eaggbf = xbfB + (size_t)NP * DD;                  // NP*256
    unsigned short* Bsw    = eaggbf + (size_t)NP * DD;                // L*2560*256
    int* hist      = (int*)(Bsw + (size_t)LL * 2560 * DD);            // M
    int* excl      = hist + MM;
    int* seg_start = excl + MM;                                       // M+1
    int* cursor    = seg_start + MM + 1;
    int* bsums     = cursor + MM;                                     // 256
    int* esrcY     = bsums + 256;                                     // E (byte offs)
    int* eid       = esrcY + NE;                                      // E
    unsigned short* etermb6 =
        (unsigned short*)(((uintptr_t)(eid + NE) + 255) & ~(uintptr_t)255); // L*NP*256
    unsigned short* Y = etermb6 + (size_t)LL * NP * DD;               // NP*2304

    // ---- CSR build ----
    hipMemsetAsync(hist, 0, MM * sizeof(int), stream);
    hist_kernel<<<(NE + 255) / 256, 256, 0, stream>>>(dstv, typev, hist);
    scan1_kernel<<<NSB, 256, 0, stream>>>(hist, excl, bsums);
    scan2_kernel<<<1, 128, 0, stream>>>(bsums);
    add_off_kernel<<<(MM + 255) / 256, 256, 0, stream>>>(excl, bsums, seg_start, cursor);
    invdeg_kernel<<<(NN + 255) / 256, 256, 0, stream>>>(seg_start, invdeg);
    sort_scatter_kernel<<<(NE + 255) / 256, 256, 0, stream>>>(srcv, dstv, typev, cursor, esrcY, eid);

    // ---- precomputes ----
    eagg_kernel<<<MM / 8, 256, 0, stream>>>(seg_start, eid, ee, invdeg, eaggbf);
    hipMemsetAsync(Whe, 0, (size_t)LL * DD * DD * sizeof(float), stream);
    whe_kernel<<<LL * 64, 256, 0, stream>>>(We, W, Whe);
    bswz_kernel<<<LL * 10 * 8 * 4, 256, 0, stream>>>(W, Wself, Whe, Bsw);
    init_x_kernel<<<(NP * DD / 4) / 256, 256, 0, stream>>>(xA, xB, xbfA, xbfB);
    eterm6_kernel<<<NGB, 512, 0, stream>>>(eaggbf, Bsw, etermb6);  // all 6 layers

    // ---- layers: Y GEMM (9 tiles), then gather/LN; x double-buffered ----
    float* xin = xA;  float* xout = xB;
    unsigned short* xbin = xbfA;  unsigned short* xbout = xbfB;
    for (int l = 0; l < LL; ++l) {
        ymm_kernel<<<NGB, 512, 0, stream>>>(xbin, Bsw + (size_t)l * 2560 * DD, Y);
        aggln_kernel<<<NN / 16, 512, 0, stream>>>(seg_start, esrcY, Y,
            etermb6 + (size_t)l * NP * DD,
            xin, gamma + (size_t)l * DD, beta + (size_t)l * DD, xout, xbout);
        float* t = xin; xin = xout; xout = t;
        unsigned short* tb = xbin; xbin = xbout; xbout = tb;
    }
    score_kernel<<<(BB * KK) / 4, 256, 0, stream>>>(batch, xin, rel_emb, out);
}

// Round 13
// 773.758 us; speedup vs baseline: 1.0893x; 1.0893x over previous
//
#include <hip/hip_runtime.h>
#include <hip/hip_bf16.h>

#define NN 20000
#define NP 20080            // padded to 80*251 (GEMM row tiles)
#define NE 320000
#define RR 8
#define DD 256
#define LL 6
#define EED 32
#define BB 64
#define KK 32
#define MM (NN * RR)        // 160000 segments, key = dst*8 + rel
#define NSB 79              // scan blocks: ceil(160000 / 2048)
#define BMR 80              // GEMM row-tile
#define NGB 251             // GEMM grid = NP / BMR (<= 256 CUs -> single round)
#define YROW 2304           // Y row: 9 tiles of 256 (r=0..7 relations, 8=self)
#define YROWB 4608          // Y row bytes
#define HSTR 260            // eterm6 Hs row stride (floats)
#define HSTRB 264           // ymm bf16 Hs row stride (ushorts)

typedef __bf16 bf8 __attribute__((ext_vector_type(8)));
typedef float f4 __attribute__((ext_vector_type(4)));

__device__ inline float lo2f(unsigned v) { return __uint_as_float(v << 16); }
__device__ inline float hi2f(unsigned v) { return __uint_as_float(v & 0xffff0000u); }
__device__ inline unsigned short f2bf(float f) {
    unsigned u = __float_as_uint(f);
    return (unsigned short)((u + 0x7fff + ((u >> 16) & 1)) >> 16);
}
__device__ inline unsigned pack2(float lo, float hi) {
    return (unsigned)f2bf(lo) | ((unsigned)f2bf(hi) << 16);
}

// global->LDS direct copy, 16B per lane. LDS dest linear (wave base + lane*16);
// swizzle lives in the per-lane GLOBAL source address (m173 pattern).
#define GLOAD_LDS16(src, dst)                                                  \
    __builtin_amdgcn_global_load_lds(                                          \
        (const __attribute__((address_space(1))) unsigned int*)(src),          \
        (__attribute__((address_space(3))) unsigned int*)(dst), 16, 0, 0)

// Raw phase barrier: order LDS ops only; global stores / loads stay in flight.
// NO memory clobber (round-2 lesson: clobber -> vmcnt(0) drain); sched_barrier
// fences compiler motion (rule #18).
#define LGKM_BARRIER()                                                         \
    do {                                                                       \
        __builtin_amdgcn_sched_barrier(0);                                     \
        asm volatile("s_waitcnt lgkmcnt(0)");                                  \
        __builtin_amdgcn_s_barrier();                                          \
        __builtin_amdgcn_sched_barrier(0);                                     \
    } while (0)

// ---------------- CSR build (once per call) ----------------

__global__ __launch_bounds__(256) void hist_kernel(const int* __restrict__ dstv,
                                                   const int* __restrict__ typev,
                                                   int* __restrict__ hist) {
    int e = blockIdx.x * 256 + threadIdx.x;
    if (e < NE) atomicAdd(&hist[dstv[e] * 8 + typev[e]], 1);
}

__global__ __launch_bounds__(256) void scan1_kernel(const int* __restrict__ hist,
                                                    int* __restrict__ excl,
                                                    int* __restrict__ bsums) {
    __shared__ int tmp[256];
    int tid = threadIdx.x;
    int base = blockIdx.x * 2048 + tid * 8;
    int v[8]; int s = 0;
#pragma unroll
    for (int i = 0; i < 8; ++i) {
        v[i] = (base + i < MM) ? hist[base + i] : 0;
        s += v[i];
    }
    tmp[tid] = s;
    __syncthreads();
    for (int off = 1; off < 256; off <<= 1) {
        int t = (tid >= off) ? tmp[tid - off] : 0;
        __syncthreads();
        tmp[tid] += t;
        __syncthreads();
    }
    int run = tmp[tid] - s;
#pragma unroll
    for (int i = 0; i < 8; ++i) {
        if (base + i < MM) excl[base + i] = run;
        run += v[i];
    }
    if (tid == 255) bsums[blockIdx.x] = tmp[255];
}

__global__ __launch_bounds__(128) void scan2_kernel(int* __restrict__ bsums) {
    __shared__ int tmp[128];
    int tid = threadIdx.x;
    int orig = (tid < NSB) ? bsums[tid] : 0;
    tmp[tid] = orig;
    __syncthreads();
    for (int off = 1; off < 128; off <<= 1) {
        int t = (tid >= off) ? tmp[tid - off] : 0;
        __syncthreads();
        tmp[tid] += t;
        __syncthreads();
    }
    if (tid < NSB) bsums[tid] = tmp[tid] - orig;
}

__global__ __launch_bounds__(256) void add_off_kernel(const int* __restrict__ excl,
                                                      const int* __restrict__ bsums,
                                                      int* __restrict__ seg_start,
                                                      int* __restrict__ cursor) {
    int i = blockIdx.x * 256 + threadIdx.x;
    if (i < MM) {
        int v = excl[i] + bsums[i >> 11];
        seg_start[i] = v;
        cursor[i] = v;
    }
    if (i == 0) seg_start[MM] = NE;
}

// scatter: pre-bake the Y gather byte-offset (src row + relation block) so the
// per-layer gather needs ZERO relation logic.
__global__ __launch_bounds__(256) void sort_scatter_kernel(
    const int* __restrict__ srcv, const int* __restrict__ dstv,
    const int* __restrict__ typev, int* __restrict__ cursor,
    int* __restrict__ esrcY, int* __restrict__ eid) {
    int e = blockIdx.x * 256 + threadIdx.x;
    if (e < NE) {
        int key = dstv[e] * 8 + typev[e];
        int pos = atomicAdd(&cursor[key], 1);
        esrcY[pos] = srcv[e] * YROWB + typev[e] * 512;
        eid[pos]   = e;
    }
}

__global__ __launch_bounds__(256) void invdeg_kernel(const int* __restrict__ seg_start,
                                                     float* __restrict__ invdeg) {
    int i = blockIdx.x * 256 + threadIdx.x;
    if (i < NN) {
        int d = seg_start[i * 8 + 8] - seg_start[i * 8];
        invdeg[i] = 1.0f / (float)max(d, 1);
    }
}

// ---------------- once-per-call precomputes ----------------

// Batched-gather eagg (round-5 lesson: serial dependent eid->ee chains left the
// wave with ~2 loads in flight -> 52us latency-bound. Issue 4 eid + 4 row loads
// per batch before accumulating, clamped indices; avg segment = 2 edges.)
__global__ __launch_bounds__(256) void eagg_kernel(
    const int* __restrict__ seg_start, const int* __restrict__ eid,
    const float* __restrict__ ee, const float* __restrict__ invdeg,
    unsigned short* __restrict__ eaggbf) {
    int tid = threadIdx.x;
    int s = blockIdx.x * 8 + (tid >> 5);
    int j = tid & 31;
    int n = s >> 3, r = s & 7;
    int j0 = seg_start[s], j1 = seg_start[s + 1];
    float sum = 0.0f;
#pragma unroll 1
    for (int p = j0; p < j1; p += 4) {
        int rem = j1 - p;
        int e4[4];
        float fv[4];
#pragma unroll
        for (int t = 0; t < 4; ++t)
            e4[t] = eid[(t < rem) ? p + t : p];        // always-valid index
#pragma unroll
        for (int t = 0; t < 4; ++t)
            fv[t] = ee[(size_t)e4[t] * EED + j];
#pragma unroll
        for (int t = 0; t < 4; ++t)
            sum += (t < rem) ? fv[t] : 0.0f;
    }
    eaggbf[(size_t)n * DD + r * EED + j] = f2bf(sum * invdeg[n]);
}

// Whe split-K over 8 d-chunks of 32, fp32 atomics (Whe pre-zeroed)
__global__ __launch_bounds__(256) void whe_kernel(const float* __restrict__ We,
                                                  const float* __restrict__ W,
                                                  float* __restrict__ Whe) {
    __shared__ float WeS[EED * 32];
    int b = blockIdx.x;
    int l = b >> 6;
    int r = (b >> 3) & 7;
    int dc = b & 7;
    int tid = threadIdx.x;
    {
        int j = tid >> 3, dl = (tid & 7) * 4;
        *(float4*)&WeS[j * 32 + dl] =
            *(const float4*)&We[(size_t)l * EED * DD + (size_t)j * DD + dc * 32 + dl];
    }
    __syncthreads();
    const float* Wr = W + ((size_t)l * 8 + r) * DD * DD + (size_t)dc * 32 * DD;
    float acc[EED];
#pragma unroll
    for (int j = 0; j < EED; ++j) acc[j] = 0.0f;
    for (int dl = 0; dl < 32; ++dl) {
        float w = Wr[(size_t)dl * DD + tid];
#pragma unroll
        for (int j = 0; j < EED; ++j) acc[j] += WeS[j * 32 + dl] * w;
    }
    float* outp = Whe + (size_t)l * DD * DD + r * EED * DD + tid;
#pragma unroll
    for (int j = 0; j < EED; ++j) unsafeAtomicAdd(&outp[j * DD], acc[j]);
}

// B pre-swizzle into MFMA fragment order (bf16).
// Tile order rt: 0..7 -> W[r=rt], 8 -> Wself, 9 -> Whe.
// Bsw[l][(((rt*8+kb)*4+quad)*256+f)*8+j] = B_l[rt][kb*32+quad*8+j][f]
__global__ __launch_bounds__(256) void bswz_kernel(const float* __restrict__ W,
                                                   const float* __restrict__ Wself,
                                                   const float* __restrict__ Whe,
                                                   unsigned short* __restrict__ Bsw) {
    int gid = blockIdx.x * 256 + threadIdx.x;
    int f = gid & 255;
    int t = gid >> 8;
    int quad = t & 3; t >>= 2;
    int kb = t & 7; t >>= 3;
    int p = t % 10, l = t / 10;
    const float* base = (p <= 7) ? W + ((size_t)l * 8 + p) * DD * DD
                      : (p == 8) ? Wself + (size_t)l * DD * DD
                                 : Whe + (size_t)l * DD * DD;
    int k0 = kb * 32 + quad * 8;
    unsigned pk[4];
#pragma unroll
    for (int jj = 0; jj < 4; ++jj)
        pk[jj] = pack2(base[(size_t)(k0 + 2 * jj) * DD + f],
                       base[(size_t)(k0 + 2 * jj + 1) * DD + f]);
    uint4 v = make_uint4(pk[0], pk[1], pk[2], pk[3]);
    *(uint4*)&Bsw[(size_t)gid * 8] = v;
}

__global__ __launch_bounds__(256) void init_x_kernel(float* __restrict__ xA,
                                                     float* __restrict__ xB,
                                                     unsigned short* __restrict__ xbfA,
                                                     unsigned short* __restrict__ xbfB) {
    int i = blockIdx.x * 256 + threadIdx.x;
    ((float4*)xA)[i] = make_float4(1.f, 1.f, 1.f, 1.f);
    ((float4*)xB)[i] = make_float4(1.f, 1.f, 1.f, 1.f);   // pad rows stay valid all layers
    ((uint2*)xbfA)[i] = make_uint2(0x3f803f80u, 0x3f803f80u);
    ((uint2*)xbfB)[i] = make_uint2(0x3f803f80u, 0x3f803f80u);
}

// ---------------- eterm precompute for ALL layers (x-independent) ----------------
// eterm_l = eaggbf @ Whe_l does not depend on x: all 6 layers computed once.
// Plain stores (NT poisoned the L3 in round 9). Runs once -> simple f32-Hs epilogue.
__global__ __launch_bounds__(512) void eterm6_kernel(
    const unsigned short* __restrict__ eaggbf, const unsigned short* __restrict__ Bsw,
    unsigned short* __restrict__ etermb6) {
    __shared__ __align__(16) unsigned char smem[40960 + BMR * HSTR * 4];
    unsigned char* As = smem;
    float* Hs = (float*)(smem + 40960);
    int tid = threadIdx.x;
    int wv = tid >> 6, lane = tid & 63;
    int row0 = blockIdx.x * BMR;
    int m = lane & 15, quad = lane >> 4;
    int col = wv * 32 + m;

#pragma unroll
    for (int i = 0; i < 5; ++i) {
        int bc = i * 512 + wv * 64;
        int c = bc + lane;
        int row = c >> 5, sc = c & 31, scs = sc ^ (row & 31);
        GLOAD_LDS16(eaggbf + (size_t)(row0 + row) * DD + scs * 8, As + (size_t)c * 16);
    }
    __syncthreads();                                 // A tile ready

#pragma unroll 1
    for (int l = 0; l < LL; ++l) {
        const unsigned short* Bswl = Bsw + (size_t)l * 2560 * DD;
        bf8 breg[2][2];
#pragma unroll
        for (int nt = 0; nt < 2; ++nt) {
            breg[0][nt] = *(const bf8*)&Bswl[(((size_t)72 * 4 + quad) * 256 + col + nt * 16) * 8];
            breg[1][nt] = *(const bf8*)&Bswl[(((size_t)73 * 4 + quad) * 256 + col + nt * 16) * 8];
        }
        f4 acc[5][2] = {};
#pragma unroll
        for (int kb = 0; kb < 8; ++kb) {
            bf8 afr[5];
#pragma unroll
            for (int mt = 0; mt < 5; ++mt) {
                int rowl = mt * 16 + m;
                afr[mt] = *(bf8*)&As[rowl * 512 + (((kb * 4 + quad) ^ (rowl & 31)) * 16)];
            }
#pragma unroll
            for (int mt = 0; mt < 5; ++mt)
#pragma unroll
                for (int nt = 0; nt < 2; ++nt)
                    acc[mt][nt] = __builtin_amdgcn_mfma_f32_16x16x32_bf16(
                        afr[mt], breg[kb & 1][nt], acc[mt][nt], 0, 0, 0);
            int gn = 72 + kb + 2;
            if (gn < 80) {
#pragma unroll
                for (int nt = 0; nt < 2; ++nt)
                    breg[kb & 1][nt] = *(const bf8*)&Bswl[((size_t)gn * 4 + quad) * 2048
                                                          + ((size_t)(col + nt * 16)) * 8];
            }
        }
        if (l > 0) LGKM_BARRIER();
#pragma unroll
        for (int mt = 0; mt < 5; ++mt)
#pragma unroll
            for (int nt = 0; nt < 2; ++nt)
#pragma unroll
                for (int rg = 0; rg < 4; ++rg)
                    Hs[(mt * 16 + quad * 4 + rg) * HSTR + wv * 32 + nt * 16 + m] = acc[mt][nt][rg];
        LGKM_BARRIER();
        unsigned short* outl = etermb6 + (size_t)l * NP * DD;
#pragma unroll
        for (int c2 = 0; c2 < 10; ++c2) {
            int li = c2 * 512 + tid;
            int row = li >> 6, u4 = li & 63;
            float4 v = *(float4*)&Hs[row * HSTR + u4 * 4];
            *(uint2*)&outl[(size_t)(row0 + row) * DD + u4 * 4] =
                make_uint2(pack2(v.x, v.y), pack2(v.z, v.w));
        }
    }
}

// ---------------- k1: dense GEMM  Y = x @ [W0..W7|Wself] ----------------
// transform-then-aggregate: Y[n][rt*256+f] = sum_k x[n][k] * Wcat[rt][k][f],
// rt 0..8. A (80 x 256) staged once; B streams L2-resident with distance-2
// register prefetch. Plain stores. Epilogue stages through a bf16 HALF-tile
// Hsb (40 rows x HSTRB, 2 passes/tile): LDS = 62KB -> 2 blocks/CU (16 waves)
// for posted-store parallelism; f2bf on the LDS-write side, global stores are
// straight uint2 copies.
__global__ __launch_bounds__(512) void ymm_kernel(
    const unsigned short* __restrict__ xbfin, const unsigned short* __restrict__ Bswl,
    unsigned short* __restrict__ Y) {
    __shared__ __align__(16) unsigned char smem[40960 + 40 * HSTRB * 2];
    unsigned char* As = smem;
    unsigned short* Hsb = (unsigned short*)(smem + 40960);
    int tid = threadIdx.x;
    int wv = tid >> 6, lane = tid & 63;
    int row0 = blockIdx.x * BMR;
    int m = lane & 15, quad = lane >> 4;

#pragma unroll
    for (int i = 0; i < 5; ++i) {
        int bc = i * 512 + wv * 64;
        int c = bc + lane;
        int row = c >> 5, sc = c & 31, scs = sc ^ (row & 31);
        GLOAD_LDS16(xbfin + (size_t)(row0 + row) * DD + scs * 8, As + (size_t)c * 16);
    }
    bf8 breg[2][2];
#pragma unroll
    for (int nt = 0; nt < 2; ++nt) {
        breg[0][nt] = *(const bf8*)&Bswl[((size_t)quad * 256 + wv * 32 + nt * 16 + m) * 8];
        breg[1][nt] = *(const bf8*)&Bswl[(((size_t)4 + quad) * 256 + wv * 32 + nt * 16 + m) * 8];
    }
    __syncthreads();                                 // A tile ready (vmcnt drain)

#pragma unroll 1
    for (int rt = 0; rt < 9; ++rt) {
        f4 acc[5][2] = {};
#pragma unroll
        for (int kb = 0; kb < 8; ++kb) {
            bf8 afr[5];
#pragma unroll
            for (int mt = 0; mt < 5; ++mt) {
                int rowl = mt * 16 + m;
                afr[mt] = *(bf8*)&As[rowl * 512 + (((kb * 4 + quad) ^ (rowl & 31)) * 16)];
            }
#pragma unroll
            for (int mt = 0; mt < 5; ++mt)
#pragma unroll
                for (int nt = 0; nt < 2; ++nt)
                    acc[mt][nt] = __builtin_amdgcn_mfma_f32_16x16x32_bf16(
                        afr[mt], breg[kb & 1][nt], acc[mt][nt], 0, 0, 0);
            int gn = rt * 8 + kb + 2;
            if (gn < 72) {                           // 9 tiles -> fragments 0..71
#pragma unroll
                for (int nt = 0; nt < 2; ++nt)
                    breg[kb & 1][nt] = *(const bf8*)&Bswl[((size_t)gn * 4 + quad) * 2048
                                                          + ((size_t)(wv * 32 + nt * 16 + m)) * 8];
            }
        }
        // ---- per-tile epilogue: 2 passes of 40 rows through bf16 Hsb ----
#pragma unroll
        for (int p = 0; p < 2; ++p) {
            if (rt > 0 || p > 0) LGKM_BARRIER();     // prior pass's Hsb reads done
#pragma unroll
            for (int mt = 0; mt < 5; ++mt)
#pragma unroll
                for (int nt = 0; nt < 2; ++nt)
#pragma unroll
                    for (int rg = 0; rg < 4; ++rg) {
                        int r = mt * 16 + quad * 4 + rg;
                        if (r >= p * 40 && r < p * 40 + 40)
                            Hsb[(r - p * 40) * HSTRB + wv * 32 + nt * 16 + m] =
                                f2bf(acc[mt][nt][rg]);
                    }
            LGKM_BARRIER();                          // Hsb writes visible
#pragma unroll
            for (int it = 0; it < 5; ++it) {
                int li = it * 512 + tid;
                int row = li >> 6, u4 = li & 63;
                uint2 v = *(uint2*)&Hsb[row * HSTRB + u4 * 4];
                *(uint2*)&Y[(size_t)(row0 + p * 40 + row) * YROW + rt * 256 + u4 * 4] = v;
            }
        }
    }
}

// ---------------- k2: fused gather + LN + residual (latency regime) ----------------
// ONE node per wave (round-13 revert: the 2-node variant raised VGPR 32->80 and
// halved the grid -> occupancy 56%->18%, total outstanding loads FELL 288->192,
// dur 46->68us. TLP beats per-wave MLP here). No LDS, no barriers; flat loop
// over all edges (relation pre-baked into esrcY byte offsets), 16-deep load
// batching; self/eterm/residual loads hoisted before the gather.
__global__ __launch_bounds__(512) void aggln_kernel(
    const int* __restrict__ seg_start, const int* __restrict__ esrcY,
    const unsigned short* __restrict__ Y, const unsigned short* __restrict__ eterml,
    const float* __restrict__ xin, const float* __restrict__ gl,
    const float* __restrict__ bl, float* __restrict__ xout,
    unsigned short* __restrict__ xbfout) {
    int tid = threadIdx.x;
    int wv = tid >> 6, lane = tid & 63;
    int n = blockIdx.x * 8 + wv;                    // grid 2500 -> n < 20000 exact
    int j0 = seg_start[n * 8], j1 = seg_start[n * 8 + 8];
    float idg = 1.0f / (float)max(j1 - j0, 1);
    const char* Yb = (const char*)Y;
    size_t lo8 = (size_t)(lane * 8);
    size_t xi = (size_t)n * DD + lane * 4;
    // hoisted independent loads (overlap the gather below)
    uint2 sv = *(const uint2*)(Yb + (size_t)n * YROWB + 4096 + lo8);   // self block
    uint2 ev = *(const uint2*)&eterml[(size_t)n * DD + lane * 4];      // edge term
    float4 xv = *(const float4*)&xin[xi];                              // residual
    float4 g  = *(const float4*)&gl[lane * 4];
    float4 bb = *(const float4*)&bl[lane * 4];
    float a0 = 0.f, a1 = 0.f, a2 = 0.f, a3 = 0.f;
#pragma unroll 1
    for (int j = j0; j < j1; j += 16) {             // avg deg = 16 -> ~1 batch
        int rem = j1 - j;
        uint2 gvv[16];
#pragma unroll
        for (int t = 0; t < 16; ++t) {
            int jj = (t < rem) ? j + t : j;         // clamp: always-valid addr
            gvv[t] = *(const uint2*)(Yb + (size_t)(unsigned)esrcY[jj] + lo8);
        }
#pragma unroll
        for (int t = 0; t < 16; ++t) {
            unsigned vx = (t < rem) ? gvv[t].x : 0u;
            unsigned vy = (t < rem) ? gvv[t].y : 0u;
            a0 += lo2f(vx); a1 += hi2f(vx);
            a2 += lo2f(vy); a3 += hi2f(vy);
        }
    }
    float h0 = a0 * idg + lo2f(sv.x) + lo2f(ev.x);
    float h1 = a1 * idg + hi2f(sv.x) + hi2f(ev.x);
    float h2 = a2 * idg + lo2f(sv.y) + lo2f(ev.y);
    float h3 = a3 * idg + hi2f(sv.y) + hi2f(ev.y);
    float s = h0 + h1 + h2 + h3;
    float q = h0 * h0 + h1 * h1 + h2 * h2 + h3 * h3;
#pragma unroll
    for (int off = 32; off; off >>= 1) {
        s += __shfl_xor(s, off);
        q += __shfl_xor(q, off);
    }
    float mu  = s * (1.0f / DD);
    float var = q * (1.0f / DD) - mu * mu;
    float rs  = rsqrtf(var + 1e-5f);
    float4 o;
    o.x = fmaxf((h0 - mu) * rs * g.x + bb.x, 0.0f) + xv.x;
    o.y = fmaxf((h1 - mu) * rs * g.y + bb.y, 0.0f) + xv.y;
    o.z = fmaxf((h2 - mu) * rs * g.z + bb.z, 0.0f) + xv.z;
    o.w = fmaxf((h3 - mu) * rs * g.w + bb.w, 0.0f) + xv.w;
    *(float4*)&xout[xi] = o;
    *(uint2*)&xbfout[xi] = make_uint2(pack2(o.x, o.y), pack2(o.z, o.w));
}

__global__ __launch_bounds__(256) void score_kernel(
    const int* __restrict__ batch, const float* __restrict__ x,
    const float* __restrict__ rel_emb, float* __restrict__ out) {
    int tid = threadIdx.x;
    int wave = tid >> 6, lane = tid & 63;
    int idx = blockIdx.x * 4 + wave;
    int s = batch[idx * 3 + 0], t = batch[idx * 3 + 1], r = batch[idx * 3 + 2];
    float4 sv = *(const float4*)&x[(size_t)s * DD + lane * 4];
    float4 tv = *(const float4*)&x[(size_t)t * DD + lane * 4];
    float4 rv = *(const float4*)&rel_emb[(size_t)r * DD + lane * 4];
    float sum = sv.x * rv.x * tv.x + sv.y * rv.y * tv.y +
                sv.z * rv.z * tv.z + sv.w * rv.w * tv.w;
#pragma unroll
    for (int off = 32; off; off >>= 1) sum += __shfl_xor(sum, off);
    if (lane == 0) out[idx] = sum;
}

extern "C" void kernel_launch(void* const* d_in, const int* in_sizes, int n_in,
                              void* d_out, int out_size, void* d_ws, size_t ws_size,
                              hipStream_t stream) {
    const int*   edge_index = (const int*)d_in[0];
    const int*   srcv   = edge_index;
    const int*   dstv   = edge_index + NE;
    const int*   typev  = (const int*)d_in[1];
    const float* ee     = (const float*)d_in[2];
    const int*   batch  = (const int*)d_in[3];
    const float* W      = (const float*)d_in[4];
    const float* Wself  = (const float*)d_in[5];
    const float* We     = (const float*)d_in[6];
    const float* gamma  = (const float*)d_in[7];
    const float* beta   = (const float*)d_in[8];
    const float* rel_emb= (const float*)d_in[9];
    float* out = (float*)d_out;

    // workspace layout (~245 MB)
    float* xA     = (float*)d_ws;                          // NP*256 f32
    float* xB     = xA + (size_t)NP * DD;                  // NP*256 f32
    float* Whe    = xB + (size_t)NP * DD;                  // L*256*256 f32
    float* invdeg = Whe + (size_t)LL * DD * DD;            // NN f32
    unsigned short* xbfA   = (unsigned short*)(invdeg + NN);          // NP*256
    unsigned short* xbfB   = xbfA + (size_t)NP * DD;                  // NP*256
    unsigned short* eaggbf = xbfB + (size_t)NP * DD;                  // NP*256
    unsigned short* Bsw    = eaggbf + (size_t)NP * DD;                // L*2560*256
    int* hist      = (int*)(Bsw + (size_t)LL * 2560 * DD);            // M
    int* excl      = hist + MM;
    int* seg_start = excl + MM;                                       // M+1
    int* cursor    = seg_start + MM + 1;
    int* bsums     = cursor + MM;                                     // 256
    int* esrcY     = bsums + 256;                                     // E (byte offs)
    int* eid       = esrcY + NE;                                      // E
    unsigned short* etermb6 =
        (unsigned short*)(((uintptr_t)(eid + NE) + 255) & ~(uintptr_t)255); // L*NP*256
    unsigned short* Y = etermb6 + (size_t)LL * NP * DD;               // NP*2304

    // ---- CSR build ----
    hipMemsetAsync(hist, 0, MM * sizeof(int), stream);
    hist_kernel<<<(NE + 255) / 256, 256, 0, stream>>>(dstv, typev, hist);
    scan1_kernel<<<NSB, 256, 0, stream>>>(hist, excl, bsums);
    scan2_kernel<<<1, 128, 0, stream>>>(bsums);
    add_off_kernel<<<(MM + 255) / 256, 256, 0, stream>>>(excl, bsums, seg_start, cursor);
    invdeg_kernel<<<(NN + 255) / 256, 256, 0, stream>>>(seg_start, invdeg);
    sort_scatter_kernel<<<(NE + 255) / 256, 256, 0, stream>>>(srcv, dstv, typev, cursor, esrcY, eid);

    // ---- precomputes ----
    eagg_kernel<<<MM / 8, 256, 0, stream>>>(seg_start, eid, ee, invdeg, eaggbf);
    hipMemsetAsync(Whe, 0, (size_t)LL * DD * DD * sizeof(float), stream);
    whe_kernel<<<LL * 64, 256, 0, stream>>>(We, W, Whe);
    bswz_kernel<<<LL * 10 * 8 * 4, 256, 0, stream>>>(W, Wself, Whe, Bsw);
    init_x_kernel<<<(NP * DD / 4) / 256, 256, 0, stream>>>(xA, xB, xbfA, xbfB);
    eterm6_kernel<<<NGB, 512, 0, stream>>>(eaggbf, Bsw, etermb6);  // all 6 layers

    // ---- layers: Y GEMM (9 tiles), then gather/LN; x double-buffered ----
    float* xin = xA;  float* xout = xB;
    unsigned short* xbin = xbfA;  unsigned short* xbout = xbfB;
    for (int l = 0; l < LL; ++l) {
        ymm_kernel<<<NGB, 512, 0, stream>>>(xbin, Bsw + (size_t)l * 2560 * DD, Y);
        aggln_kernel<<<NN / 8, 512, 0, stream>>>(seg_start, esrcY, Y,
            etermb6 + (size_t)l * NP * DD,
            xin, gamma + (size_t)l * DD, beta + (size_t)l * DD, xout, xbout);
        float* t = xin; xin = xout; xout = t;
        unsigned short* tb = xbin; xbin = xbout; xbout = tb;
    }
    score_kernel<<<(BB * KK) / 4, 256, 0, stream>>>(batch, xin, rel_emb, out);
}

// Round 14
// 727.171 us; speedup vs baseline: 1.1590x; 1.0641x over previous
//
#include <hip/hip_runtime.h>
#include <hip/hip_bf16.h>

#define NN 20000
#define NP 20080            // padded to 80*251 (GEMM row tiles)
#define NE 320000
#define RR 8
#define DD 256
#define LL 6
#define EED 32
#define BB 64
#define KK 32
#define MM (NN * RR)        // 160000 segments, key = dst*8 + rel
#define NSB 79              // scan blocks: ceil(160000 / 2048)
#define BMR 80              // GEMM row-tile
#define NGB 251             // eterm6 grid = NP / BMR
#define NGB2 502            // ymm grid: 251 row-blocks x 2 col-halves -> 2 blk/CU
#define YROW 2304           // Y row: 9 tiles of 256 (r=0..7 relations, 8=self)
#define YROWB 4608          // Y row bytes
#define HSTR 260            // eterm6 Hs row stride (floats)
#define HSTRB 272           // ymm bf16 Hsb row stride (ushorts): 544B = 8-bank rot,
                            // quads land on disjoint bank octets (2-way = free)

typedef __bf16 bf8 __attribute__((ext_vector_type(8)));
typedef float f4 __attribute__((ext_vector_type(4)));

__device__ inline float lo2f(unsigned v) { return __uint_as_float(v << 16); }
__device__ inline float hi2f(unsigned v) { return __uint_as_float(v & 0xffff0000u); }
__device__ inline unsigned short f2bf(float f) {
    unsigned u = __float_as_uint(f);
    return (unsigned short)((u + 0x7fff + ((u >> 16) & 1)) >> 16);
}
__device__ inline unsigned pack2(float lo, float hi) {
    return (unsigned)f2bf(lo) | ((unsigned)f2bf(hi) << 16);
}

// global->LDS direct copy, 16B per lane. LDS dest linear (wave base + lane*16);
// swizzle lives in the per-lane GLOBAL source address (m173 pattern).
#define GLOAD_LDS16(src, dst)                                                  \
    __builtin_amdgcn_global_load_lds(                                          \
        (const __attribute__((address_space(1))) unsigned int*)(src),          \
        (__attribute__((address_space(3))) unsigned int*)(dst), 16, 0, 0)

// Raw phase barrier: order LDS ops only; global stores / loads stay in flight.
// NO memory clobber (round-2 lesson: clobber -> vmcnt(0) drain); sched_barrier
// fences compiler motion (rule #18).
#define LGKM_BARRIER()                                                         \
    do {                                                                       \
        __builtin_amdgcn_sched_barrier(0);                                     \
        asm volatile("s_waitcnt lgkmcnt(0)");                                  \
        __builtin_amdgcn_s_barrier();                                          \
        __builtin_amdgcn_sched_barrier(0);                                     \
    } while (0)

// ---------------- CSR build (once per call) ----------------

__global__ __launch_bounds__(256) void hist_kernel(const int* __restrict__ dstv,
                                                   const int* __restrict__ typev,
                                                   int* __restrict__ hist) {
    int e = blockIdx.x * 256 + threadIdx.x;
    if (e < NE) atomicAdd(&hist[dstv[e] * 8 + typev[e]], 1);
}

__global__ __launch_bounds__(256) void scan1_kernel(const int* __restrict__ hist,
                                                    int* __restrict__ excl,
                                                    int* __restrict__ bsums) {
    __shared__ int tmp[256];
    int tid = threadIdx.x;
    int base = blockIdx.x * 2048 + tid * 8;
    int v[8]; int s = 0;
#pragma unroll
    for (int i = 0; i < 8; ++i) {
        v[i] = (base + i < MM) ? hist[base + i] : 0;
        s += v[i];
    }
    tmp[tid] = s;
    __syncthreads();
    for (int off = 1; off < 256; off <<= 1) {
        int t = (tid >= off) ? tmp[tid - off] : 0;
        __syncthreads();
        tmp[tid] += t;
        __syncthreads();
    }
    int run = tmp[tid] - s;
#pragma unroll
    for (int i = 0; i < 8; ++i) {
        if (base + i < MM) excl[base + i] = run;
        run += v[i];
    }
    if (tid == 255) bsums[blockIdx.x] = tmp[255];
}

__global__ __launch_bounds__(128) void scan2_kernel(int* __restrict__ bsums) {
    __shared__ int tmp[128];
    int tid = threadIdx.x;
    int orig = (tid < NSB) ? bsums[tid] : 0;
    tmp[tid] = orig;
    __syncthreads();
    for (int off = 1; off < 128; off <<= 1) {
        int t = (tid >= off) ? tmp[tid - off] : 0;
        __syncthreads();
        tmp[tid] += t;
        __syncthreads();
    }
    if (tid < NSB) bsums[tid] = tmp[tid] - orig;
}

__global__ __launch_bounds__(256) void add_off_kernel(const int* __restrict__ excl,
                                                      const int* __restrict__ bsums,
                                                      int* __restrict__ seg_start,
                                                      int* __restrict__ cursor) {
    int i = blockIdx.x * 256 + threadIdx.x;
    if (i < MM) {
        int v = excl[i] + bsums[i >> 11];
        seg_start[i] = v;
        cursor[i] = v;
    }
    if (i == 0) seg_start[MM] = NE;
}

// scatter: pre-bake the Y gather byte-offset (src row + relation block) so the
// per-layer gather needs ZERO relation logic.
__global__ __launch_bounds__(256) void sort_scatter_kernel(
    const int* __restrict__ srcv, const int* __restrict__ dstv,
    const int* __restrict__ typev, int* __restrict__ cursor,
    int* __restrict__ esrcY, int* __restrict__ eid) {
    int e = blockIdx.x * 256 + threadIdx.x;
    if (e < NE) {
        int key = dstv[e] * 8 + typev[e];
        int pos = atomicAdd(&cursor[key], 1);
        esrcY[pos] = srcv[e] * YROWB + typev[e] * 512;
        eid[pos]   = e;
    }
}

__global__ __launch_bounds__(256) void invdeg_kernel(const int* __restrict__ seg_start,
                                                     float* __restrict__ invdeg) {
    int i = blockIdx.x * 256 + threadIdx.x;
    if (i < NN) {
        int d = seg_start[i * 8 + 8] - seg_start[i * 8];
        invdeg[i] = 1.0f / (float)max(d, 1);
    }
}

// ---------------- once-per-call precomputes ----------------

// Batched-gather eagg (round-5 lesson: serial dependent eid->ee chains left the
// wave with ~2 loads in flight -> 52us latency-bound. Issue 4 eid + 4 row loads
// per batch before accumulating, clamped indices; avg segment = 2 edges.)
__global__ __launch_bounds__(256) void eagg_kernel(
    const int* __restrict__ seg_start, const int* __restrict__ eid,
    const float* __restrict__ ee, const float* __restrict__ invdeg,
    unsigned short* __restrict__ eaggbf) {
    int tid = threadIdx.x;
    int s = blockIdx.x * 8 + (tid >> 5);
    int j = tid & 31;
    int n = s >> 3, r = s & 7;
    int j0 = seg_start[s], j1 = seg_start[s + 1];
    float sum = 0.0f;
#pragma unroll 1
    for (int p = j0; p < j1; p += 4) {
        int rem = j1 - p;
        int e4[4];
        float fv[4];
#pragma unroll
        for (int t = 0; t < 4; ++t)
            e4[t] = eid[(t < rem) ? p + t : p];        // always-valid index
#pragma unroll
        for (int t = 0; t < 4; ++t)
            fv[t] = ee[(size_t)e4[t] * EED + j];
#pragma unroll
        for (int t = 0; t < 4; ++t)
            sum += (t < rem) ? fv[t] : 0.0f;
    }
    eaggbf[(size_t)n * DD + r * EED + j] = f2bf(sum * invdeg[n]);
}

// Whe split-K over 8 d-chunks of 32, fp32 atomics (Whe pre-zeroed)
__global__ __launch_bounds__(256) void whe_kernel(const float* __restrict__ We,
                                                  const float* __restrict__ W,
                                                  float* __restrict__ Whe) {
    __shared__ float WeS[EED * 32];
    int b = blockIdx.x;
    int l = b >> 6;
    int r = (b >> 3) & 7;
    int dc = b & 7;
    int tid = threadIdx.x;
    {
        int j = tid >> 3, dl = (tid & 7) * 4;
        *(float4*)&WeS[j * 32 + dl] =
            *(const float4*)&We[(size_t)l * EED * DD + (size_t)j * DD + dc * 32 + dl];
    }
    __syncthreads();
    const float* Wr = W + ((size_t)l * 8 + r) * DD * DD + (size_t)dc * 32 * DD;
    float acc[EED];
#pragma unroll
    for (int j = 0; j < EED; ++j) acc[j] = 0.0f;
    for (int dl = 0; dl < 32; ++dl) {
        float w = Wr[(size_t)dl * DD + tid];
#pragma unroll
        for (int j = 0; j < EED; ++j) acc[j] += WeS[j * 32 + dl] * w;
    }
    float* outp = Whe + (size_t)l * DD * DD + r * EED * DD + tid;
#pragma unroll
    for (int j = 0; j < EED; ++j) unsafeAtomicAdd(&outp[j * DD], acc[j]);
}

// B pre-swizzle into MFMA fragment order (bf16).
// Tile order rt: 0..7 -> W[r=rt], 8 -> Wself, 9 -> Whe.
// Bsw[l][(((rt*8+kb)*4+quad)*256+f)*8+j] = B_l[rt][kb*32+quad*8+j][f]
__global__ __launch_bounds__(256) void bswz_kernel(const float* __restrict__ W,
                                                   const float* __restrict__ Wself,
                                                   const float* __restrict__ Whe,
                                                   unsigned short* __restrict__ Bsw) {
    int gid = blockIdx.x * 256 + threadIdx.x;
    int f = gid & 255;
    int t = gid >> 8;
    int quad = t & 3; t >>= 2;
    int kb = t & 7; t >>= 3;
    int p = t % 10, l = t / 10;
    const float* base = (p <= 7) ? W + ((size_t)l * 8 + p) * DD * DD
                      : (p == 8) ? Wself + (size_t)l * DD * DD
                                 : Whe + (size_t)l * DD * DD;
    int k0 = kb * 32 + quad * 8;
    unsigned pk[4];
#pragma unroll
    for (int jj = 0; jj < 4; ++jj)
        pk[jj] = pack2(base[(size_t)(k0 + 2 * jj) * DD + f],
                       base[(size_t)(k0 + 2 * jj + 1) * DD + f]);
    uint4 v = make_uint4(pk[0], pk[1], pk[2], pk[3]);
    *(uint4*)&Bsw[(size_t)gid * 8] = v;
}

__global__ __launch_bounds__(256) void init_x_kernel(float* __restrict__ xA,
                                                     float* __restrict__ xB,
                                                     unsigned short* __restrict__ xbfA,
                                                     unsigned short* __restrict__ xbfB) {
    int i = blockIdx.x * 256 + threadIdx.x;
    ((float4*)xA)[i] = make_float4(1.f, 1.f, 1.f, 1.f);
    ((float4*)xB)[i] = make_float4(1.f, 1.f, 1.f, 1.f);   // pad rows stay valid all layers
    ((uint2*)xbfA)[i] = make_uint2(0x3f803f80u, 0x3f803f80u);
    ((uint2*)xbfB)[i] = make_uint2(0x3f803f80u, 0x3f803f80u);
}

// ---------------- eterm precompute for ALL layers (x-independent) ----------------
// eterm_l = eaggbf @ Whe_l does not depend on x: all 6 layers computed once.
// Plain stores (NT poisoned the L3 in round 9). Runs once -> simple f32-Hs epilogue.
__global__ __launch_bounds__(512) void eterm6_kernel(
    const unsigned short* __restrict__ eaggbf, const unsigned short* __restrict__ Bsw,
    unsigned short* __restrict__ etermb6) {
    __shared__ __align__(16) unsigned char smem[40960 + BMR * HSTR * 4];
    unsigned char* As = smem;
    float* Hs = (float*)(smem + 40960);
    int tid = threadIdx.x;
    int wv = tid >> 6, lane = tid & 63;
    int row0 = blockIdx.x * BMR;
    int m = lane & 15, quad = lane >> 4;
    int col = wv * 32 + m;

#pragma unroll
    for (int i = 0; i < 5; ++i) {
        int bc = i * 512 + wv * 64;
        int c = bc + lane;
        int row = c >> 5, sc = c & 31, scs = sc ^ (row & 31);
        GLOAD_LDS16(eaggbf + (size_t)(row0 + row) * DD + scs * 8, As + (size_t)c * 16);
    }
    __syncthreads();                                 // A tile ready

#pragma unroll 1
    for (int l = 0; l < LL; ++l) {
        const unsigned short* Bswl = Bsw + (size_t)l * 2560 * DD;
        bf8 breg[2][2];
#pragma unroll
        for (int nt = 0; nt < 2; ++nt) {
            breg[0][nt] = *(const bf8*)&Bswl[(((size_t)72 * 4 + quad) * 256 + col + nt * 16) * 8];
            breg[1][nt] = *(const bf8*)&Bswl[(((size_t)73 * 4 + quad) * 256 + col + nt * 16) * 8];
        }
        f4 acc[5][2] = {};
#pragma unroll
        for (int kb = 0; kb < 8; ++kb) {
            bf8 afr[5];
#pragma unroll
            for (int mt = 0; mt < 5; ++mt) {
                int rowl = mt * 16 + m;
                afr[mt] = *(bf8*)&As[rowl * 512 + (((kb * 4 + quad) ^ (rowl & 31)) * 16)];
            }
#pragma unroll
            for (int mt = 0; mt < 5; ++mt)
#pragma unroll
                for (int nt = 0; nt < 2; ++nt)
                    acc[mt][nt] = __builtin_amdgcn_mfma_f32_16x16x32_bf16(
                        afr[mt], breg[kb & 1][nt], acc[mt][nt], 0, 0, 0);
            int gn = 72 + kb + 2;
            if (gn < 80) {
#pragma unroll
                for (int nt = 0; nt < 2; ++nt)
                    breg[kb & 1][nt] = *(const bf8*)&Bswl[((size_t)gn * 4 + quad) * 2048
                                                          + ((size_t)(col + nt * 16)) * 8];
            }
        }
        if (l > 0) LGKM_BARRIER();
#pragma unroll
        for (int mt = 0; mt < 5; ++mt)
#pragma unroll
            for (int nt = 0; nt < 2; ++nt)
#pragma unroll
                for (int rg = 0; rg < 4; ++rg)
                    Hs[(mt * 16 + quad * 4 + rg) * HSTR + wv * 32 + nt * 16 + m] = acc[mt][nt][rg];
        LGKM_BARRIER();
        unsigned short* outl = etermb6 + (size_t)l * NP * DD;
#pragma unroll
        for (int c2 = 0; c2 < 10; ++c2) {
            int li = c2 * 512 + tid;
            int row = li >> 6, u4 = li & 63;
            float4 v = *(float4*)&Hs[row * HSTR + u4 * 4];
            *(uint2*)&outl[(size_t)(row0 + row) * DD + u4 * 4] =
                make_uint2(pack2(v.x, v.y), pack2(v.z, v.w));
        }
    }
}

// ---------------- k1: dense GEMM  Y = x @ [W0..W7|Wself] ----------------
// Round-14: N-SPLIT for real occupancy. r13 showed LDS reduction alone can't
// raise occupancy: grid=251 < 256 CUs means 1 block/CU is structural. Block now
// computes 80 rows x 128 COLS (col-half nh = blockIdx&1): grid 502 -> 2 blocks
// resident/CU = 16 waves (vs 8). Per wave: 16 cols, acc[5] (halves acc VGPR).
// Epilogue: 16-row bf16 Hsb pass per mt tile (pass p == mt p, exact 512-thread
// copy), LDS 40960+8704=49.7KB. A staged by both col-halves (+10MB L2/layer,
// negligible); B reads split by half -> same total.
__global__ __launch_bounds__(512) void ymm_kernel(
    const unsigned short* __restrict__ xbfin, const unsigned short* __restrict__ Bswl,
    unsigned short* __restrict__ Y) {
    __shared__ __align__(16) unsigned char smem[40960 + 16 * HSTRB * 2];
    unsigned char* As = smem;
    unsigned short* Hsb = (unsigned short*)(smem + 40960);
    int tid = threadIdx.x;
    int wv = tid >> 6, lane = tid & 63;
    int nh = blockIdx.x & 1;
    int row0 = (blockIdx.x >> 1) * BMR;
    int m = lane & 15, quad = lane >> 4;
    int colb = nh * 128 + wv * 16 + m;              // this wave's B-fragment column

#pragma unroll
    for (int i = 0; i < 5; ++i) {
        int bc = i * 512 + wv * 64;
        int c = bc + lane;
        int row = c >> 5, sc = c & 31, scs = sc ^ (row & 31);
        GLOAD_LDS16(xbfin + (size_t)(row0 + row) * DD + scs * 8, As + (size_t)c * 16);
    }
    bf8 breg[2];
    breg[0] = *(const bf8*)&Bswl[((size_t)quad * 256 + colb) * 8];
    breg[1] = *(const bf8*)&Bswl[(((size_t)4 + quad) * 256 + colb) * 8];
    __syncthreads();                                 // A tile ready (vmcnt drain)

#pragma unroll 1
    for (int rt = 0; rt < 9; ++rt) {
        f4 acc[5] = {};
#pragma unroll
        for (int kb = 0; kb < 8; ++kb) {
            bf8 afr[5];
#pragma unroll
            for (int mt = 0; mt < 5; ++mt) {
                int rowl = mt * 16 + m;
                afr[mt] = *(bf8*)&As[rowl * 512 + (((kb * 4 + quad) ^ (rowl & 31)) * 16)];
            }
#pragma unroll
            for (int mt = 0; mt < 5; ++mt)
                acc[mt] = __builtin_amdgcn_mfma_f32_16x16x32_bf16(
                    afr[mt], breg[kb & 1], acc[mt], 0, 0, 0);
            int gn = rt * 8 + kb + 2;
            if (gn < 72)                             // 9 tiles -> fragments 0..71
                breg[kb & 1] = *(const bf8*)&Bswl[((size_t)gn * 4 + quad) * 2048
                                                  + (size_t)colb * 8];
        }
        // ---- epilogue: 5 passes (pass p = mt tile p), 16 rows each ----
#pragma unroll
        for (int p = 0; p < 5; ++p) {
            if (rt > 0 || p > 0) LGKM_BARRIER();     // prior pass's Hsb reads done
#pragma unroll
            for (int rg = 0; rg < 4; ++rg)
                Hsb[(quad * 4 + rg) * HSTRB + wv * 16 + m] = f2bf(acc[p][rg]);
            LGKM_BARRIER();                          // Hsb writes visible
            int row = tid >> 5, u = tid & 31;        // 16 rows x 128 cols exactly
            uint2 v = *(uint2*)&Hsb[row * HSTRB + u * 4];
            *(uint2*)&Y[(size_t)(row0 + p * 16 + row) * YROW + rt * 256 + nh * 128 + u * 4] = v;
        }
    }
}

// ---------------- k2: fused gather + LN + residual (latency regime) ----------------
// ONE node per wave (r12 lesson: 2-node variant raised VGPR 32->80, halved grid,
// occupancy 56->18%, total outstanding loads FELL -> dur 46->68us. TLP beats
// per-wave MLP). No LDS, no barriers; flat loop over all edges (relation
// pre-baked into esrcY), 16-deep load batching; independent loads hoisted.
__global__ __launch_bounds__(512) void aggln_kernel(
    const int* __restrict__ seg_start, const int* __restrict__ esrcY,
    const unsigned short* __restrict__ Y, const unsigned short* __restrict__ eterml,
    const float* __restrict__ xin, const float* __restrict__ gl,
    const float* __restrict__ bl, float* __restrict__ xout,
    unsigned short* __restrict__ xbfout) {
    int tid = threadIdx.x;
    int wv = tid >> 6, lane = tid & 63;
    int n = blockIdx.x * 8 + wv;                    // grid 2500 -> n < 20000 exact
    int j0 = seg_start[n * 8], j1 = seg_start[n * 8 + 8];
    float idg = 1.0f / (float)max(j1 - j0, 1);
    const char* Yb = (const char*)Y;
    size_t lo8 = (size_t)(lane * 8);
    size_t xi = (size_t)n * DD + lane * 4;
    // hoisted independent loads (overlap the gather below)
    uint2 sv = *(const uint2*)(Yb + (size_t)n * YROWB + 4096 + lo8);   // self block
    uint2 ev = *(const uint2*)&eterml[(size_t)n * DD + lane * 4];      // edge term
    float4 xv = *(const float4*)&xin[xi];                              // residual
    float4 g  = *(const float4*)&gl[lane * 4];
    float4 bb = *(const float4*)&bl[lane * 4];
    float a0 = 0.f, a1 = 0.f, a2 = 0.f, a3 = 0.f;
#pragma unroll 1
    for (int j = j0; j < j1; j += 16) {             // avg deg = 16 -> ~1 batch
        int rem = j1 - j;
        uint2 gvv[16];
#pragma unroll
        for (int t = 0; t < 16; ++t) {
            int jj = (t < rem) ? j + t : j;         // clamp: always-valid addr
            gvv[t] = *(const uint2*)(Yb + (size_t)(unsigned)esrcY[jj] + lo8);
        }
#pragma unroll
        for (int t = 0; t < 16; ++t) {
            unsigned vx = (t < rem) ? gvv[t].x : 0u;
            unsigned vy = (t < rem) ? gvv[t].y : 0u;
            a0 += lo2f(vx); a1 += hi2f(vx);
            a2 += lo2f(vy); a3 += hi2f(vy);
        }
    }
    float h0 = a0 * idg + lo2f(sv.x) + lo2f(ev.x);
    float h1 = a1 * idg + hi2f(sv.x) + hi2f(ev.x);
    float h2 = a2 * idg + lo2f(sv.y) + lo2f(ev.y);
    float h3 = a3 * idg + hi2f(sv.y) + hi2f(ev.y);
    float s = h0 + h1 + h2 + h3;
    float q = h0 * h0 + h1 * h1 + h2 * h2 + h3 * h3;
#pragma unroll
    for (int off = 32; off; off >>= 1) {
        s += __shfl_xor(s, off);
        q += __shfl_xor(q, off);
    }
    float mu  = s * (1.0f / DD);
    float var = q * (1.0f / DD) - mu * mu;
    float rs  = rsqrtf(var + 1e-5f);
    float4 o;
    o.x = fmaxf((h0 - mu) * rs * g.x + bb.x, 0.0f) + xv.x;
    o.y = fmaxf((h1 - mu) * rs * g.y + bb.y, 0.0f) + xv.y;
    o.z = fmaxf((h2 - mu) * rs * g.z + bb.z, 0.0f) + xv.z;
    o.w = fmaxf((h3 - mu) * rs * g.w + bb.w, 0.0f) + xv.w;
    *(float4*)&xout[xi] = o;
    *(uint2*)&xbfout[xi] = make_uint2(pack2(o.x, o.y), pack2(o.z, o.w));
}

__global__ __launch_bounds__(256) void score_kernel(
    const int* __restrict__ batch, const float* __restrict__ x,
    const float* __restrict__ rel_emb, float* __restrict__ out) {
    int tid = threadIdx.x;
    int wave = tid >> 6, lane = tid & 63;
    int idx = blockIdx.x * 4 + wave;
    int s = batch[idx * 3 + 0], t = batch[idx * 3 + 1], r = batch[idx * 3 + 2];
    float4 sv = *(const float4*)&x[(size_t)s * DD + lane * 4];
    float4 tv = *(const float4*)&x[(size_t)t * DD + lane * 4];
    float4 rv = *(const float4*)&rel_emb[(size_t)r * DD + lane * 4];
    float sum = sv.x * rv.x * tv.x + sv.y * rv.y * tv.y +
                sv.z * rv.z * tv.z + sv.w * rv.w * tv.w;
#pragma unroll
    for (int off = 32; off; off >>= 1) sum += __shfl_xor(sum, off);
    if (lane == 0) out[idx] = sum;
}

extern "C" void kernel_launch(void* const* d_in, const int* in_sizes, int n_in,
                              void* d_out, int out_size, void* d_ws, size_t ws_size,
                              hipStream_t stream) {
    const int*   edge_index = (const int*)d_in[0];
    const int*   srcv   = edge_index;
    const int*   dstv   = edge_index + NE;
    const int*   typev  = (const int*)d_in[1];
    const float* ee     = (const float*)d_in[2];
    const int*   batch  = (const int*)d_in[3];
    const float* W      = (const float*)d_in[4];
    const float* Wself  = (const float*)d_in[5];
    const float* We     = (const float*)d_in[6];
    const float* gamma  = (const float*)d_in[7];
    const float* beta   = (const float*)d_in[8];
    const float* rel_emb= (const float*)d_in[9];
    float* out = (float*)d_out;

    // workspace layout (~245 MB)
    float* xA     = (float*)d_ws;                          // NP*256 f32
    float* xB     = xA + (size_t)NP * DD;                  // NP*256 f32
    float* Whe    = xB + (size_t)NP * DD;                  // L*256*256 f32
    float* invdeg = Whe + (size_t)LL * DD * DD;            // NN f32
    unsigned short* xbfA   = (unsigned short*)(invdeg + NN);          // NP*256
    unsigned short* xbfB   = xbfA + (size_t)NP * DD;                  // NP*256
    unsigned short* eaggbf = xbfB + (size_t)NP * DD;                  // NP*256
    unsigned short* Bsw    = eaggbf + (size_t)NP * DD;                // L*2560*256
    int* hist      = (int*)(Bsw + (size_t)LL * 2560 * DD);            // M
    int* excl      = hist + MM;
    int* seg_start = excl + MM;                                       // M+1
    int* cursor    = seg_start + MM + 1;
    int* bsums     = cursor + MM;                                     // 256
    int* esrcY     = bsums + 256;                                     // E (byte offs)
    int* eid       = esrcY + NE;                                      // E
    unsigned short* etermb6 =
        (unsigned short*)(((uintptr_t)(eid + NE) + 255) & ~(uintptr_t)255); // L*NP*256
    unsigned short* Y = etermb6 + (size_t)LL * NP * DD;               // NP*2304

    // ---- CSR build ----
    hipMemsetAsync(hist, 0, MM * sizeof(int), stream);
    hist_kernel<<<(NE + 255) / 256, 256, 0, stream>>>(dstv, typev, hist);
    scan1_kernel<<<NSB, 256, 0, stream>>>(hist, excl, bsums);
    scan2_kernel<<<1, 128, 0, stream>>>(bsums);
    add_off_kernel<<<(MM + 255) / 256, 256, 0, stream>>>(excl, bsums, seg_start, cursor);
    invdeg_kernel<<<(NN + 255) / 256, 256, 0, stream>>>(seg_start, invdeg);
    sort_scatter_kernel<<<(NE + 255) / 256, 256, 0, stream>>>(srcv, dstv, typev, cursor, esrcY, eid);

    // ---- precomputes ----
    eagg_kernel<<<MM / 8, 256, 0, stream>>>(seg_start, eid, ee, invdeg, eaggbf);
    hipMemsetAsync(Whe, 0, (size_t)LL * DD * DD * sizeof(float), stream);
    whe_kernel<<<LL * 64, 256, 0, stream>>>(We, W, Whe);
    bswz_kernel<<<LL * 10 * 8 * 4, 256, 0, stream>>>(W, Wself, Whe, Bsw);
    init_x_kernel<<<(NP * DD / 4) / 256, 256, 0, stream>>>(xA, xB, xbfA, xbfB);
    eterm6_kernel<<<NGB, 512, 0, stream>>>(eaggbf, Bsw, etermb6);  // all 6 layers

    // ---- layers: Y GEMM (9 tiles, col-split grid), then gather/LN ----
    float* xin = xA;  float* xout = xB;
    unsigned short* xbin = xbfA;  unsigned short* xbout = xbfB;
    for (int l = 0; l < LL; ++l) {
        ymm_kernel<<<NGB2, 512, 0, stream>>>(xbin, Bsw + (size_t)l * 2560 * DD, Y);
        aggln_kernel<<<NN / 8, 512, 0, stream>>>(seg_start, esrcY, Y,
            etermb6 + (size_t)l * NP * DD,
            xin, gamma + (size_t)l * DD, beta + (size_t)l * DD, xout, xbout);
        float* t = xin; xin = xout; xout = t;
        unsigned short* tb = xbin; xbin = xbout; xbout = tb;
    }
    score_kernel<<<(BB * KK) / 4, 256, 0, stream>>>(batch, xin, rel_emb, out);
}